// Round 6
// baseline (191.707 us; speedup 1.0000x reference)
//
#include <hip/hip_runtime.h>
#include <hip/hip_fp16.h>
#include <cstdint>

// Problem constants
#define BB 8
#define NN 256
#define NC 5
#define NH 8
#define DIM 512
#define HD 64

typedef _Float16 half_t;
typedef _Float16 h8 __attribute__((ext_vector_type(8)));
typedef _Float16 h4 __attribute__((ext_vector_type(4)));
typedef float f4 __attribute__((ext_vector_type(4)));
typedef uint32_t u4v __attribute__((ext_vector_type(4)));

__device__ __forceinline__ f4 mfma16(h8 a, h8 b, f4 c) {
  return __builtin_amdgcn_mfma_f32_16x16x32_f16(a, b, c, 0, 0, 0);
}

__device__ __forceinline__ h8 ld_f32x8_h8(const float* __restrict__ p) {
  float4 a = *(const float4*)p;
  float4 b = *(const float4*)(p + 4);
  h8 r;
  r[0] = (_Float16)a.x; r[1] = (_Float16)a.y; r[2] = (_Float16)a.z; r[3] = (_Float16)a.w;
  r[4] = (_Float16)b.x; r[5] = (_Float16)b.y; r[6] = (_Float16)b.z; r[7] = (_Float16)b.w;
  return r;
}

static __device__ const h8 HZERO = {(_Float16)0, (_Float16)0, (_Float16)0, (_Float16)0,
                                    (_Float16)0, (_Float16)0, (_Float16)0, (_Float16)0};

__device__ __forceinline__ h8 relu_pos_h8(h8 x) {
#if __has_builtin(__builtin_elementwise_max)
  return __builtin_elementwise_max(x, HZERO);
#else
  u4v u = __builtin_bit_cast(u4v, x);
  const u4v k1 = {0x00010001u, 0x00010001u, 0x00010001u, 0x00010001u};
  u4v s = (u >> 15) & k1;
  u4v m = (s << 16) - s;
  u = u & ~m;
  return __builtin_bit_cast(h8, u);
#endif
}

__device__ __forceinline__ h8 relu_neg_h8(h8 x) {
#if __has_builtin(__builtin_elementwise_max)
  return __builtin_elementwise_max(-x, HZERO);
#else
  u4v u = __builtin_bit_cast(u4v, x);
  const u4v k1 = {0x00010001u, 0x00010001u, 0x00010001u, 0x00010001u};
  const u4v ks = {0x80008000u, 0x80008000u, 0x80008000u, 0x80008000u};
  u4v s = (u >> 15) & k1;
  u4v m = (s << 16) - s;
  u = (u ^ ks) & m;
  return __builtin_bit_cast(h8, u);
#endif
}

// Raw barrier: waits LDS only, does NOT drain vmcnt (global stores stay in flight).
__device__ __forceinline__ void barrier_lds() {
  __builtin_amdgcn_sched_barrier(0);
  asm volatile("s_waitcnt lgkmcnt(0)" ::: "memory");
  __builtin_amdgcn_s_barrier();
  asm volatile("" ::: "memory");
  __builtin_amdgcn_sched_barrier(0);
}

// ---------------------------------------------------------------------------
// K1: all three projections in one launch.
//   bx <  32: q  = x @ qk_w^T       -> q_h [2048][512] fp16
//   bx <  52: k  = anchors @ qk_w^T -> k_h [1280][512] fp16
//   else    : vT = (x @ v_w^T)^T    -> vT  [512][2048] fp16  ([h*64+d][b*256+m])
// ---------------------------------------------------------------------------
__global__ __launch_bounds__(256) void proj_all(const float* __restrict__ x,
                                                const float* __restrict__ anchors,
                                                const float* __restrict__ qk_w,
                                                const float* __restrict__ v_w,
                                                half_t* __restrict__ q_h,
                                                half_t* __restrict__ k_h,
                                                half_t* __restrict__ vT) {
  const int bx = blockIdx.x, by = blockIdx.y;
  const int tid = threadIdx.x;
  const int w = tid >> 6, lane = tid & 63;
  const int lr = lane & 15, lk = (lane >> 4) * 8, lg = lane >> 4;

  const float* A;
  const float* W;
  int mode, rt0;
  if (bx < 32)      { A = x;       W = qk_w; mode = 0; rt0 = bx * 64; }
  else if (bx < 52) { A = anchors; W = qk_w; mode = 1; rt0 = (bx - 32) * 64; }
  else              { A = x;       W = v_w;  mode = 2; rt0 = (bx - 52) * 64; }

  const int row0 = rt0 + w * 16;
  const int col0 = by * 64;
  const f4 fz = {0.f, 0.f, 0.f, 0.f};
  f4 acc[4] = {fz, fz, fz, fz};
  const float* arow = A + (size_t)(row0 + lr) * DIM;

  if (mode != 2) {
    for (int k0 = 0; k0 < DIM; k0 += 32) {
      h8 a = ld_f32x8_h8(arow + k0 + lk);
#pragma unroll
      for (int ct = 0; ct < 4; ++ct) {
        h8 b = ld_f32x8_h8(W + (size_t)(col0 + ct * 16 + lr) * DIM + k0 + lk);
        acc[ct] = mfma16(a, b, acc[ct]);
      }
    }
    half_t* out = (mode == 0) ? q_h : k_h;
#pragma unroll
    for (int ct = 0; ct < 4; ++ct) {
      int col = col0 + ct * 16 + lr;
#pragma unroll
      for (int r = 0; r < 4; ++r) {
        int row = row0 + lg * 4 + r;
        out[(size_t)row * DIM + col] = (half_t)acc[ct][r];
      }
    }
  } else {
    for (int k0 = 0; k0 < DIM; k0 += 32) {
      h8 a = ld_f32x8_h8(arow + k0 + lk);
#pragma unroll
      for (int ct = 0; ct < 4; ++ct) {
        h8 b = ld_f32x8_h8(W + (size_t)(col0 + ct * 16 + lr) * DIM + k0 + lk);
        acc[ct] = mfma16(b, a, acc[ct]);
      }
    }
    const int xrow = row0 + lr;
#pragma unroll
    for (int ct = 0; ct < 4; ++ct) {
#pragma unroll
      for (int r = 0; r < 4; ++r) {
        int col = col0 + ct * 16 + lg * 4 + r;  // = h*64 + d
        vT[(size_t)col * (BB * NN) + xrow] = (half_t)acc[ct][r];
      }
    }
  }
}

// ---------------------------------------------------------------------------
// K2 v6: 2 half-blocks per (b,c,h), split on OUTPUT COLUMNS n' (a0 rows used
// as the R operand). 1024 thr = 16 waves. FULL a0 [256][256] fp16 in LDS.
//  phase1: wave w computes a0[16 rows n0=w*16][all 256 m]; writes fp16 to a0s
//          (all waves) and fp32 to d_out (only rows of this block's half).
//  S: waves as (ng=w>>1, cg=w&1): 32n x 64n' tile; La/R both read from a0s.
//  softmax over n per n'-column: wave-local (max,sum) -> scr, one combine.
//  PV: P transposed via per-wave swizzled [32][72] LDS buffer; vT half staged
//      in dead a0s region; cg-pair partials reduced through LDS (f32).
// LDS: a0s 128K (reused: vst 16K + pbuf 72K / upart 68K) + scr 8K + scr2 1K.
// ---------------------------------------------------------------------------
__global__ __launch_bounds__(1024) void fused_attn6(const half_t* __restrict__ q_h,
                                                    const half_t* __restrict__ k_h,
                                                    const half_t* __restrict__ vT,
                                                    const float* __restrict__ weights,
                                                    float* __restrict__ a0_base,
                                                    half_t* __restrict__ U4) {
  extern __shared__ char smem[];
  half_t* a0s = (half_t*)smem;                       // [256][256] swz, 131072 B
  half_t* vst = (half_t*)smem;                       // reuse: [64][128] swz, 16 KB
  half_t* pbuf = (half_t*)(smem + 16384);            // reuse: 16 x [32][72], 72 KB
  float* upart = (float*)(smem + 16384);             // reuse: 8 x [32][68] f32
  float2* scr = (float2*)(smem + 131072);            // [8 ng][128 n'], 8192 B
  float2* scr2 = (float2*)(smem + 131072 + 8192);    // [128 n'] (gm,sg), 1024 B

  const int id = blockIdx.x;  // 640 = 8*5*8*2
  const int b = id / 80;
  const int rem = id % 80;
  const int c = rem / 16;
  const int h = (rem >> 1) & 7;
  const int q = rem & 1;

  const int tid = threadIdx.x;
  const int w = tid >> 6, lane = tid & 63;
  const int lr = lane & 15, lk = (lane >> 4) * 8, lg = lane >> 4;
  const int n0 = w * 16;           // phase-1 row assignment
  const int ng = w >> 1, cg = w & 1;
  const int sn0 = ng * 32;         // S-phase row assignment

  const half_t* qb = q_h + (size_t)(b * NN) * DIM + h * HD;
  const half_t* kb = k_h + (size_t)(c * NN) * DIM + h * HD;
  const half_t* vTb = vT + (size_t)(h * HD) * (BB * NN) + b * NN;
  float* a0out = a0_base + (size_t)((b * NC + c) * NH + h) * (NN * NN);
  const float wgt = weights[(b * NH + h) * NC + c];

  const f4 fz = {0.f, 0.f, 0.f, 0.f};

  // ---- phase 1: a0[w's 16 rows][all m]; k fragments straight from L2 ----
  h8 qf0 = *(const h8*)(qb + (size_t)(n0 + lr) * DIM + lk);
  h8 qf1 = *(const h8*)(qb + (size_t)(n0 + lr) * DIM + 32 + lk);
  const bool myhalf = ((w >> 3) == q);
  const int na = n0 + lr;
#pragma unroll
  for (int mt = 0; mt < 16; ++mt) {
    h8 kf0 = *(const h8*)(kb + (size_t)(mt * 16 + lr) * DIM + lk);
    h8 kf1 = *(const h8*)(kb + (size_t)(mt * 16 + lr) * DIM + 32 + lk);
    f4 acc = mfma16(kf0, qf0, fz);
    acc = mfma16(kf1, qf1, acc);
    const int mb = mt * 16 + lg * 4;
    f4 v0;
    h4 hv;
#pragma unroll
    for (int r = 0; r < 4; ++r) {
      v0[r] = acc[r] * 0.125f;
      hv[r] = (_Float16)v0[r];
    }
    if (myhalf) *(f4*)(a0out + (size_t)na * NN + mb) = v0;
    *(h4*)(a0s + ((na * NN + mb) ^ ((na & 7) << 3))) = hv;
  }
  barrier_lds();  // A: a0s complete

  // ---- La = relu(-a0) for this wave's 32 S-rows ----
  h8 La[2][8];
#pragma unroll
  for (int nt = 0; nt < 2; ++nt)
#pragma unroll
    for (int kc = 0; kc < 8; ++kc) {
      int row = sn0 + nt * 16 + lr;
      La[nt][kc] = relu_neg_h8(*(const h8*)(a0s + ((row * NN + kc * 32 + lk) ^ ((row & 7) << 3))));
    }

  // ---- S = L @ R^T over this wave's 64 n'-columns ----
  f4 sacc[4][2];
#pragma unroll
  for (int ct = 0; ct < 4; ++ct)
#pragma unroll
    for (int nt = 0; nt < 2; ++nt) sacc[ct][nt] = fz;
#pragma unroll
  for (int kc = 0; kc < 8; ++kc) {
#pragma unroll
    for (int ct = 0; ct < 4; ++ct) {
      const int rrow = q * 128 + cg * 64 + ct * 16 + lr;
      h8 R = relu_pos_h8(*(const h8*)(a0s + ((rrow * NN + kc * 32 + lk) ^ ((rrow & 7) << 3))));
      sacc[ct][0] = mfma16(La[0][kc], R, sacc[ct][0]);
      sacc[ct][1] = mfma16(La[1][kc], R, sacc[ct][1]);
    }
  }

  // ---- wave-local (max,sum) per n'-col; exp in place ----
  float mw[4];
#pragma unroll
  for (int ct = 0; ct < 4; ++ct) {
    float v = 0.f;  // S >= 0 always
#pragma unroll
    for (int nt = 0; nt < 2; ++nt)
#pragma unroll
      for (int r = 0; r < 4; ++r) v = fmaxf(v, sacc[ct][nt][r]);
    v = fmaxf(v, __shfl_xor(v, 16, 64));
    v = fmaxf(v, __shfl_xor(v, 32, 64));
    mw[ct] = v;
    float s = 0.f;
#pragma unroll
    for (int nt = 0; nt < 2; ++nt)
#pragma unroll
      for (int r = 0; r < 4; ++r) {
        float e = __expf(sacc[ct][nt][r] - v);
        sacc[ct][nt][r] = e;
        s += e;
      }
    s += __shfl_xor(s, 16, 64);
    s += __shfl_xor(s, 32, 64);
    if (lane < 16) {
      float2 t;
      t.x = v;
      t.y = s;
      scr[ng * 128 + cg * 64 + ct * 16 + lane] = t;
    }
  }
  barrier_lds();  // C: scr complete, all a0s reads done

  // ---- combine across 8 n-groups (threads 0..127) ∥ stage vT half ----
  if (tid < 128) {
    float gm = 0.f;
#pragma unroll
    for (int ww = 0; ww < 8; ++ww) gm = fmaxf(gm, scr[ww * 128 + tid].x);
    float sg = 0.f;
#pragma unroll
    for (int ww = 0; ww < 8; ++ww) {
      float2 t = scr[ww * 128 + tid];
      sg += t.y * __expf(t.x - gm);
    }
    float2 r;
    r.x = gm;
    r.y = sg;
    scr2[tid] = r;
  }
  {
    int d = tid >> 4, m8 = (tid & 15) * 8;
    h8 vv = *(const h8*)(vTb + (size_t)d * (BB * NN) + q * 128 + m8);
    *(h8*)(vst + ((d * 128 + m8) ^ ((d & 7) << 4))) = vv;
  }
  barrier_lds();  // D: scr2 + vst ready

  float fac[4];
#pragma unroll
  for (int ct = 0; ct < 4; ++ct) {
    float2 t = scr2[cg * 64 + ct * 16 + lr];
    fac[ct] = __expf(mw[ct] - t.x) * wgt / t.y;
  }

  // ---- P transpose into per-wave swizzled buffer [32 n][72 (64 n' + pad)] ----
  half_t* pbw = pbuf + w * 2304;
#pragma unroll
  for (int ct = 0; ct < 4; ++ct)
#pragma unroll
    for (int nt = 0; nt < 2; ++nt)
#pragma unroll
      for (int r = 0; r < 4; ++r) {
        int row = nt * 16 + lg * 4 + r;
        int col = (ct * 16 + lr) ^ ((row & 7) << 3);
        pbw[row * 72 + col] = (_Float16)(sacc[ct][nt][r] * fac[ct]);
      }

  // ---- PV: U[n 32][d 64] partial over this wave's 64 n' ----
  f4 uacc[4][2];
#pragma unroll
  for (int dt = 0; dt < 4; ++dt)
#pragma unroll
    for (int nt = 0; nt < 2; ++nt) uacc[dt][nt] = fz;
#pragma unroll
  for (int kk = 0; kk < 2; ++kk) {
    h8 pf[2];
#pragma unroll
    for (int nt = 0; nt < 2; ++nt) {
      int row = nt * 16 + lr;
      pf[nt] = *(const h8*)(pbw + row * 72 + ((kk * 32 + lk) ^ ((row & 7) << 3)));
    }
#pragma unroll
    for (int dt = 0; dt < 4; ++dt) {
      int drow = dt * 16 + lr;
      h8 vf = *(const h8*)(vst + ((drow * 128 + cg * 64 + kk * 32 + lk) ^ ((drow & 7) << 4)));
      uacc[dt][0] = mfma16(vf, pf[0], uacc[dt][0]);
      uacc[dt][1] = mfma16(vf, pf[1], uacc[dt][1]);
    }
  }
  barrier_lds();  // E: PV done, pbuf dead

  // ---- cg-pair reduction through LDS, single fp16 U4 store ----
  float* up = upart + ng * (32 * 68);
  if (cg == 1) {
#pragma unroll
    for (int dt = 0; dt < 4; ++dt)
#pragma unroll
      for (int nt = 0; nt < 2; ++nt)
        *(f4*)(up + (nt * 16 + lr) * 68 + dt * 16 + lg * 4) = uacc[dt][nt];
  }
  barrier_lds();  // F
  if (cg == 0) {
    half_t* U4b = U4 + (size_t)(((b * NC + c) * NH + h) * 2 + q) * (NN * HD);
#pragma unroll
    for (int dt = 0; dt < 4; ++dt)
#pragma unroll
      for (int nt = 0; nt < 2; ++nt) {
        f4 o = uacc[dt][nt] + *(const f4*)(up + (nt * 16 + lr) * 68 + dt * 16 + lg * 4);
        h4 hv;
#pragma unroll
        for (int r = 0; r < 4; ++r) hv[r] = (_Float16)o[r];
        *(h4*)(U4b + (size_t)(sn0 + nt * 16 + lr) * HD + dt * 16 + lg * 4) = hv;
      }
  }
}

// ---------------------------------------------------------------------------
// K3: merged reduce + out-projection. 64 blocks, one per 32 output rows
// (= one (b, hh) pair). Stage reduced A-tile (sum of 10 U4 partials) in LDS,
// then GEMM vs proj_w^T, add bias.
// ---------------------------------------------------------------------------
__global__ __launch_bounds__(256) void out_projA(const half_t* __restrict__ U4,
                                                 const float* __restrict__ pw,
                                                 const float* __restrict__ pb,
                                                 float* __restrict__ out0) {
  __shared__ half_t Ast[32 * 520];  // [32 rows][512 k + 8 pad]
  const int bid = blockIdx.x;       // 64
  const int b = bid >> 3, hh = bid & 7;
  const int tid = threadIdx.x;

  // stage: thread (il = tid>>3, kk = tid&7) reduces 10 partial slices
  {
    const int il = tid >> 3, kk = tid & 7;
    const int n = (il << 3) | kk;
    const half_t* base = U4 + ((size_t)(b * NC * NH + hh) * 2) * (NN * HD) + (size_t)n * HD;
#pragma unroll
    for (int d0 = 0; d0 < HD; d0 += 8) {
      float a8[8] = {0.f, 0.f, 0.f, 0.f, 0.f, 0.f, 0.f, 0.f};
#pragma unroll
      for (int cc = 0; cc < NC; ++cc)
#pragma unroll
        for (int qq = 0; qq < 2; ++qq) {
          h8 u = *(const h8*)(base + (size_t)(cc * NH * 2 + qq) * (NN * HD) + d0);
#pragma unroll
          for (int j = 0; j < 8; ++j) a8[j] += (float)u[j];
        }
      h8 o;
#pragma unroll
      for (int j = 0; j < 8; ++j) o[j] = (_Float16)a8[j];
      *(h8*)(&Ast[il * 520 + kk * 64 + d0]) = o;
    }
  }
  __syncthreads();

  // GEMM: 4 waves x 128 cols each, 32 rows
  const int w = tid >> 6, lane = tid & 63;
  const int lr = lane & 15, lk = (lane >> 4) * 8, lg = lane >> 4;
  const int col0 = w * 128;
  const f4 fz = {0.f, 0.f, 0.f, 0.f};
  f4 acc[2][8];
#pragma unroll
  for (int rt = 0; rt < 2; ++rt)
#pragma unroll
    for (int ct = 0; ct < 8; ++ct) acc[rt][ct] = fz;

  for (int kc = 0; kc < 16; ++kc) {
    h8 a0f = *(const h8*)(&Ast[(lr)*520 + kc * 32 + lk]);
    h8 a1f = *(const h8*)(&Ast[(16 + lr) * 520 + kc * 32 + lk]);
#pragma unroll
    for (int ct = 0; ct < 8; ++ct) {
      h8 bf = ld_f32x8_h8(pw + (size_t)(col0 + ct * 16 + lr) * DIM + kc * 32 + lk);
      acc[0][ct] = mfma16(a0f, bf, acc[0][ct]);
      acc[1][ct] = mfma16(a1f, bf, acc[1][ct]);
    }
  }

  const int row_base = b * NN + hh * 32;
#pragma unroll
  for (int ct = 0; ct < 8; ++ct) {
    int col = col0 + ct * 16 + lr;
    float bias = pb[col];
#pragma unroll
    for (int rt = 0; rt < 2; ++rt)
#pragma unroll
      for (int r = 0; r < 4; ++r) {
        int row = row_base + rt * 16 + lg * 4 + r;
        out0[(size_t)row * DIM + col] = acc[rt][ct][r] + bias;
      }
  }
}

// ---------------------------------------------------------------------------
extern "C" void kernel_launch(void* const* d_in, const int* in_sizes, int n_in,
                              void* d_out, int out_size, void* d_ws, size_t ws_size,
                              hipStream_t stream) {
  const float* x = (const float*)d_in[0];
  const float* anchors = (const float*)d_in[1];
  const float* weights = (const float*)d_in[2];
  const float* qk_w = (const float*)d_in[3];
  const float* v_w = (const float*)d_in[4];
  const float* proj_w = (const float*)d_in[5];
  const float* proj_b = (const float*)d_in[6];

  float* out0 = (float*)d_out;                       // [8,256,512]
  float* a0_out = out0 + (size_t)BB * NN * DIM;      // [8,5,8,256,256]

  char* ws = (char*)d_ws;
  half_t* q_h = (half_t*)ws;                                   // 2 MB
  half_t* k_h = (half_t*)(ws + (size_t)2 * 1024 * 1024);       // 1.25 MB
  half_t* vT = (half_t*)(ws + (size_t)4 * 1024 * 1024);        // 2 MB
  half_t* U4 = (half_t*)(ws + (size_t)8 * 1024 * 1024);        // 20 MB

  proj_all<<<dim3(84, 8), 256, 0, stream>>>(x, anchors, qk_w, v_w, q_h, k_h, vT);

  const size_t lds_bytes = 131072 + 8192 + 1024;  // 140,288 B
  fused_attn6<<<dim3(BB * NC * NH * 2), 1024, lds_bytes, stream>>>(q_h, k_h, vT, weights,
                                                                   a0_out, U4);

  out_projA<<<dim3(64), 256, 0, stream>>>(U4, proj_w, proj_b, out0);

  (void)in_sizes; (void)n_in; (void)out_size; (void)ws_size;
}

// Round 7
// 116.351 us; speedup vs baseline: 1.6477x; 1.6477x over previous
//
#include <hip/hip_runtime.h>
#include <hip/hip_fp16.h>
#include <cstdint>

// Problem constants
#define BB 8
#define NN 256
#define NC 5
#define NH 8
#define DIM 512
#define HD 64

typedef _Float16 half_t;
typedef _Float16 h8 __attribute__((ext_vector_type(8)));
typedef _Float16 h4 __attribute__((ext_vector_type(4)));
typedef float f4 __attribute__((ext_vector_type(4)));
typedef uint32_t u4v __attribute__((ext_vector_type(4)));

__device__ __forceinline__ f4 mfma16(h8 a, h8 b, f4 c) {
  return __builtin_amdgcn_mfma_f32_16x16x32_f16(a, b, c, 0, 0, 0);
}

static __device__ const h8 HZERO = {(_Float16)0, (_Float16)0, (_Float16)0, (_Float16)0,
                                    (_Float16)0, (_Float16)0, (_Float16)0, (_Float16)0};

__device__ __forceinline__ h8 relu_pos_h8(h8 x) {
#if __has_builtin(__builtin_elementwise_max)
  return __builtin_elementwise_max(x, HZERO);
#else
  u4v u = __builtin_bit_cast(u4v, x);
  const u4v k1 = {0x00010001u, 0x00010001u, 0x00010001u, 0x00010001u};
  u4v s = (u >> 15) & k1;
  u4v m = (s << 16) - s;
  u = u & ~m;
  return __builtin_bit_cast(h8, u);
#endif
}

__device__ __forceinline__ h8 relu_neg_h8(h8 x) {
#if __has_builtin(__builtin_elementwise_max)
  return __builtin_elementwise_max(-x, HZERO);
#else
  u4v u = __builtin_bit_cast(u4v, x);
  const u4v k1 = {0x00010001u, 0x00010001u, 0x00010001u, 0x00010001u};
  const u4v ks = {0x80008000u, 0x80008000u, 0x80008000u, 0x80008000u};
  u4v s = (u >> 15) & k1;
  u4v m = (s << 16) - s;
  u = (u ^ ks) & m;
  return __builtin_bit_cast(h8, u);
#endif
}

// Raw barrier: waits LDS only, does NOT drain vmcnt (global stores stay in flight).
__device__ __forceinline__ void barrier_lds() {
  __builtin_amdgcn_sched_barrier(0);
  asm volatile("s_waitcnt lgkmcnt(0)" ::: "memory");
  __builtin_amdgcn_s_barrier();
  asm volatile("" ::: "memory");
  __builtin_amdgcn_sched_barrier(0);
}

// ---------------------------------------------------------------------------
// K0: convert x, anchors, qk_w, v_w, proj_w to fp16 (one f4->h4 per thread).
// chunks: x 262144 | anchors 163840 | qk 65536 | v 65536 | proj 65536
// ---------------------------------------------------------------------------
__global__ __launch_bounds__(256) void cvt_all(const float* __restrict__ x,
                                               const float* __restrict__ anchors,
                                               const float* __restrict__ qk_w,
                                               const float* __restrict__ v_w,
                                               const float* __restrict__ proj_w,
                                               half_t* __restrict__ x_h,
                                               half_t* __restrict__ anc_h,
                                               half_t* __restrict__ qk_h,
                                               half_t* __restrict__ v_wh,
                                               half_t* __restrict__ pw_h) {
  int i = blockIdx.x * 256 + threadIdx.x;
  const float* src;
  half_t* dst;
  int off;
  if (i < 262144)      { src = x;       dst = x_h;   off = i; }
  else if (i < 425984) { src = anchors; dst = anc_h; off = i - 262144; }
  else if (i < 491520) { src = qk_w;    dst = qk_h;  off = i - 425984; }
  else if (i < 557056) { src = v_w;     dst = v_wh;  off = i - 491520; }
  else                 { src = proj_w;  dst = pw_h;  off = i - 557056; }
  float4 v = ((const float4*)src)[off];
  h4 o;
  o[0] = (_Float16)v.x; o[1] = (_Float16)v.y; o[2] = (_Float16)v.z; o[3] = (_Float16)v.w;
  ((h4*)dst)[off] = o;
}

// ---------------------------------------------------------------------------
// K1: all three projections (pure fp16 operands).
//   bx <  32: q  = x_h @ qk_h^T   -> q_h [2048][512]
//   bx <  52: k  = anc_h @ qk_h^T -> k_h [1280][512]
//   else    : vT = (x_h @ v_wh^T)^T -> vT [512][2048]  ([h*64+d][b*256+m])
// ---------------------------------------------------------------------------
__global__ __launch_bounds__(256) void proj_all(const half_t* __restrict__ x_h,
                                                const half_t* __restrict__ anc_h,
                                                const half_t* __restrict__ qk_h,
                                                const half_t* __restrict__ v_wh,
                                                half_t* __restrict__ q_h,
                                                half_t* __restrict__ k_h,
                                                half_t* __restrict__ vT) {
  const int bx = blockIdx.x, by = blockIdx.y;
  const int tid = threadIdx.x;
  const int w = tid >> 6, lane = tid & 63;
  const int lr = lane & 15, lk = (lane >> 4) * 8, lg = lane >> 4;

  const half_t* A;
  const half_t* W;
  int mode, rt0;
  if (bx < 32)      { A = x_h;   W = qk_h; mode = 0; rt0 = bx * 64; }
  else if (bx < 52) { A = anc_h; W = qk_h; mode = 1; rt0 = (bx - 32) * 64; }
  else              { A = x_h;   W = v_wh; mode = 2; rt0 = (bx - 52) * 64; }

  const int row0 = rt0 + w * 16;
  const int col0 = by * 64;
  const f4 fz = {0.f, 0.f, 0.f, 0.f};
  f4 acc[4] = {fz, fz, fz, fz};
  const half_t* arow = A + (size_t)(row0 + lr) * DIM;

  if (mode != 2) {
    for (int k0 = 0; k0 < DIM; k0 += 32) {
      h8 a = *(const h8*)(arow + k0 + lk);
#pragma unroll
      for (int ct = 0; ct < 4; ++ct) {
        h8 b = *(const h8*)(W + (size_t)(col0 + ct * 16 + lr) * DIM + k0 + lk);
        acc[ct] = mfma16(a, b, acc[ct]);
      }
    }
    half_t* out = (mode == 0) ? q_h : k_h;
#pragma unroll
    for (int ct = 0; ct < 4; ++ct) {
      int col = col0 + ct * 16 + lr;
#pragma unroll
      for (int r = 0; r < 4; ++r) {
        int row = row0 + lg * 4 + r;
        out[(size_t)row * DIM + col] = (half_t)acc[ct][r];
      }
    }
  } else {
    for (int k0 = 0; k0 < DIM; k0 += 32) {
      h8 a = *(const h8*)(arow + k0 + lk);
#pragma unroll
      for (int ct = 0; ct < 4; ++ct) {
        h8 b = *(const h8*)(W + (size_t)(col0 + ct * 16 + lr) * DIM + k0 + lk);
        acc[ct] = mfma16(b, a, acc[ct]);
      }
    }
    const int xrow = row0 + lr;
#pragma unroll
    for (int ct = 0; ct < 4; ++ct) {
#pragma unroll
      for (int r = 0; r < 4; ++r) {
        int col = col0 + ct * 16 + lg * 4 + r;  // = h*64 + d
        vT[(size_t)col * (BB * NN) + xrow] = (half_t)acc[ct][r];
      }
    }
  }
}

// ---------------------------------------------------------------------------
// K2 (round-5 winner, unchanged): 2 half-blocks per (b,c,h), 1024 thr.
// ---------------------------------------------------------------------------
__global__ __launch_bounds__(1024, 4) void fused_attn5(const half_t* __restrict__ q_h,
                                                       const half_t* __restrict__ k_h,
                                                       const half_t* __restrict__ vT,
                                                       const float* __restrict__ weights,
                                                       float* __restrict__ a0_base,
                                                       half_t* __restrict__ U4) {
  extern __shared__ char smem[];
  half_t* a0s = (half_t*)smem;                        // [128][256] swz, 65536 B
  half_t* kst = (half_t*)(smem + 65536);              // [256][64] swz, 32768 B
  half_t* vst = kst;                                  // reuse: [64][128] swz, 16384 B
  half_t* wbuf = (half_t*)(smem + 98304);             // 16 waves x 640 h
  float2* scr = (float2*)(smem + 118784);             // [16 w][128 m'] f2, 16384 B
  float2* scr2 = (float2*)(smem + 135168);            // [128 m'] f2 (gm, sg), 1024 B

  const int id = blockIdx.x;          // 640 = 8*5*8*2
  const int b = id / 80;
  const int rem = id % 80;
  const int c = rem / 16;
  const int h = (rem >> 1) & 7;
  const int q = rem & 1;

  const int tid = threadIdx.x;
  const int w = tid >> 6, lane = tid & 63;
  const int lr = lane & 15, lk = (lane >> 4) * 8, lg = lane >> 4;
  const int n0 = w * 16;

  const half_t* qb = q_h + (size_t)(b * NN) * DIM + h * HD;
  const half_t* kb = k_h + (size_t)(c * NN) * DIM + h * HD;
  const half_t* vTb = vT + (size_t)(h * HD) * (BB * NN) + b * NN;
  float* a0out = a0_base + (size_t)((b * NC + c) * NH + h) * (NN * NN);
  const float wgt = weights[(b * NH + h) * NC + c];

  const f4 fz = {0.f, 0.f, 0.f, 0.f};

  // q fragments for this wave's 16 rows
  h8 qf0 = *(const h8*)(qb + (size_t)(n0 + lr) * DIM + lk);
  h8 qf1 = *(const h8*)(qb + (size_t)(n0 + lr) * DIM + 32 + lk);

  // ---- stage k tile [256][64] fp16, swizzled ----
#pragma unroll
  for (int pass = 0; pass < 2; ++pass) {
    int slot = pass * 1024 + tid;
    int row = slot >> 3, k8 = (slot & 7) * 8;
    h8 val = *(const h8*)(kb + (size_t)row * DIM + k8);
    *(h8*)(kst + ((row * 64 + k8) ^ ((row & 7) << 3))) = val;
  }
  barrier_lds();  // A

  // ---- phase 1: full a0 for L; half rows -> global fp32 + LDS fp16 ----
  half_t* Lb = wbuf + w * 640;  // [16][40]
  h8 La[8];
  const bool myhalf = ((w >> 3) == q);
  const int rl = (w & 7) * 16 + lr;  // local a0s row when myhalf
#pragma unroll
  for (int mt = 0; mt < 16; ++mt) {
    const int krow = mt * 16 + lr;
    h8 kf0 = *(const h8*)(kst + ((krow * 64 + lk) ^ ((krow & 7) << 3)));
    h8 kf1 = *(const h8*)(kst + ((krow * 64 + 32 + lk) ^ ((krow & 7) << 3)));
    f4 acc = mfma16(kf0, qf0, fz);
    acc = mfma16(kf1, qf1, acc);
    f4 v0;
    h4 hv;
#pragma unroll
    for (int r = 0; r < 4; ++r) {
      v0[r] = acc[r] * 0.125f;
      hv[r] = (_Float16)v0[r];
    }
    *(h4*)(Lb + lr * 40 + (mt & 1) * 16 + lg * 4) = hv;
    if (myhalf) {
      *(f4*)(a0out + (size_t)(n0 + lr) * NN + mt * 16 + lg * 4) = v0;
      *(h4*)(a0s + ((rl * 256 + mt * 16 + lg * 4) ^ ((rl & 7) << 3))) = hv;
    }
    if (mt & 1) {
      h8 raw = *(const h8*)(Lb + lr * 40 + lg * 8);
      La[mt >> 1] = relu_neg_h8(raw);
    }
  }
  barrier_lds();  // B (a0s ready; kst reads done)

  // ---- stage vT half-tile [64 d][128 m'] into dead kst region ----
  {
    int d = tid >> 4, m8 = (tid & 15) * 8;
    h8 val = *(const h8*)(vTb + (size_t)d * (BB * NN) + q * 128 + m8);
    *(h8*)(vst + ((d * 128 + m8) ^ ((d & 7) << 4))) = val;
  }

  // ---- S = L @ R^T over this block's 128 m' columns ----
  f4 sacc[8];
#pragma unroll
  for (int ct = 0; ct < 8; ++ct) sacc[ct] = fz;
#pragma unroll
  for (int kc = 0; kc < 8; ++kc) {
#pragma unroll
    for (int ct = 0; ct < 8; ++ct) {
      const int rr = ct * 16 + lr;
      h8 R = relu_pos_h8(*(const h8*)(a0s + ((rr * 256 + kc * 32 + lk) ^ ((rr & 7) << 3))));
      sacc[ct] = mfma16(La[kc], R, sacc[ct]);
    }
  }

  // ---- per-wave (max, sum) per column; exp in place ----
  float mw[8];
#pragma unroll
  for (int ct = 0; ct < 8; ++ct) {
    float v = 0.f;  // S >= 0 always
#pragma unroll
    for (int r = 0; r < 4; ++r) v = fmaxf(v, sacc[ct][r]);
    v = fmaxf(v, __shfl_xor(v, 16, 64));
    v = fmaxf(v, __shfl_xor(v, 32, 64));
    mw[ct] = v;
    float s = 0.f;
#pragma unroll
    for (int r = 0; r < 4; ++r) {
      float e = __expf(sacc[ct][r] - v);
      sacc[ct][r] = e;
      s += e;
    }
    s += __shfl_xor(s, 16, 64);
    s += __shfl_xor(s, 32, 64);
    if (lane < 16) {
      float2 t;
      t.x = v;
      t.y = s;
      scr[w * 128 + ct * 16 + lr] = t;
    }
  }
  barrier_lds();  // C

  // ---- combine across 16 waves: 128 threads, one column each ----
  if (tid < 128) {
    float gm = 0.f;
#pragma unroll
    for (int ww = 0; ww < 16; ++ww) gm = fmaxf(gm, scr[ww * 128 + tid].x);
    float sg = 0.f;
#pragma unroll
    for (int ww = 0; ww < 16; ++ww) {
      float2 t = scr[ww * 128 + tid];
      sg += t.y * __expf(t.x - gm);
    }
    float2 r;
    r.x = gm;
    r.y = sg;
    scr2[tid] = r;
  }
  barrier_lds();  // D

  float fac[8];
#pragma unroll
  for (int ct = 0; ct < 8; ++ct) {
    float2 t = scr2[ct * 16 + lr];
    fac[ct] = __expf(mw[ct] - t.x) * wgt / t.y;
  }

  // ---- PV: per 32-col panel, transpose-bounce P then MFMA with vst ----
  half_t* pbw = wbuf + w * 640;  // [32][20]
  f4 uacc[4] = {fz, fz, fz, fz};
#pragma unroll
  for (int pan = 0; pan < 4; ++pan) {
#pragma unroll
    for (int ctl = 0; ctl < 2; ++ctl) {
      const int ct = pan * 2 + ctl;
      h4 hv;
#pragma unroll
      for (int r = 0; r < 4; ++r) hv[r] = (_Float16)(sacc[ct][r] * fac[ct]);
      *(h4*)(pbw + (ctl * 16 + lr) * 20 + lg * 4) = hv;
    }
    h8 pf;
#pragma unroll
    for (int e = 0; e < 8; ++e) pf[e] = pbw[(lg * 8 + e) * 20 + lr];
#pragma unroll
    for (int dt = 0; dt < 4; ++dt) {
      const int dr = dt * 16 + lr;
      h8 vf = *(const h8*)(vst + ((dr * 128 + pan * 32 + lk) ^ ((dr & 7) << 4)));
      uacc[dt] = mfma16(vf, pf, uacc[dt]);
    }
  }

  // ---- store partial U4 (fp16): [n][d] ----
  half_t* U4b = U4 + (size_t)(((b * NC + c) * NH + h) * 2 + q) * (NN * HD);
#pragma unroll
  for (int dt = 0; dt < 4; ++dt) {
    h4 hv;
#pragma unroll
    for (int r = 0; r < 4; ++r) hv[r] = (_Float16)uacc[dt][r];
    *(h4*)(U4b + (size_t)(n0 + lr) * HD + dt * 16 + lg * 4) = hv;
  }
}

// ---------------------------------------------------------------------------
// K3: out_head[b,h] = sum over (c, half) of U4 partials
// ---------------------------------------------------------------------------
__global__ __launch_bounds__(256) void reduce_u(const half_t* __restrict__ U4,
                                                half_t* __restrict__ out_head) {
  int t = blockIdx.x * 256 + threadIdx.x;  // 131072 threads
  int bh = t >> 11;
  int e = (t & 2047) * 8;
  int b = bh >> 3, h = bh & 7;
  float acc[8] = {0.f, 0.f, 0.f, 0.f, 0.f, 0.f, 0.f, 0.f};
#pragma unroll
  for (int c = 0; c < NC; ++c)
#pragma unroll
    for (int qq = 0; qq < 2; ++qq) {
      h8 u = *(const h8*)(U4 + (size_t)(((b * NC + c) * NH + h) * 2 + qq) * (NN * HD) + e);
#pragma unroll
      for (int j = 0; j < 8; ++j) acc[j] += (float)u[j];
    }
  h8 o;
#pragma unroll
  for (int j = 0; j < 8; ++j) o[j] = (_Float16)acc[j];
  *(h8*)(out_head + (size_t)bh * (NN * HD) + e) = o;
}

// ---------------------------------------------------------------------------
// K4: out0 = reshape(out_head) @ pw_h^T + proj_b  (fp16 weights)
// ---------------------------------------------------------------------------
__global__ __launch_bounds__(256) void out_proj(const half_t* __restrict__ out_head,
                                                const half_t* __restrict__ pw_h,
                                                const float* __restrict__ pb,
                                                float* __restrict__ out0) {
  const int tid = threadIdx.x;
  const int w = tid >> 6, lane = tid & 63;
  const int lr = lane & 15, lk = (lane >> 4) * 8, lg = lane >> 4;
  const int row0 = blockIdx.x * 64 + w * 16;
  const int col0 = blockIdx.y * 64;
  const int r_ = row0 + lr;
  const int b = r_ >> 8, i = r_ & 255;
  const int hh = i >> 5;
  const f4 fz = {0.f, 0.f, 0.f, 0.f};
  f4 acc[4] = {fz, fz, fz, fz};
  for (int k0 = 0; k0 < DIM; k0 += 32) {
    const int k = k0 + lk;
    const int n = ((i & 31) << 3) | (k >> 6);
    const int d = k & 63;
    h8 a = *(const h8*)(out_head + (size_t)((b * NH + hh) * NN + n) * HD + d);
#pragma unroll
    for (int ct = 0; ct < 4; ++ct) {
      h8 bf = *(const h8*)(pw_h + (size_t)(col0 + ct * 16 + lr) * DIM + k0 + lk);
      acc[ct] = mfma16(a, bf, acc[ct]);
    }
  }
#pragma unroll
  for (int ct = 0; ct < 4; ++ct) {
    int col = col0 + ct * 16 + lr;
    float bias = pb[col];
#pragma unroll
    for (int r = 0; r < 4; ++r) {
      int row = row0 + lg * 4 + r;
      out0[(size_t)row * DIM + col] = acc[ct][r] + bias;
    }
  }
}

// ---------------------------------------------------------------------------
extern "C" void kernel_launch(void* const* d_in, const int* in_sizes, int n_in,
                              void* d_out, int out_size, void* d_ws, size_t ws_size,
                              hipStream_t stream) {
  const float* x = (const float*)d_in[0];
  const float* anchors = (const float*)d_in[1];
  const float* weights = (const float*)d_in[2];
  const float* qk_w = (const float*)d_in[3];
  const float* v_w = (const float*)d_in[4];
  const float* proj_w = (const float*)d_in[5];
  const float* proj_b = (const float*)d_in[6];

  float* out0 = (float*)d_out;                       // [8,256,512]
  float* a0_out = out0 + (size_t)BB * NN * DIM;      // [8,5,8,256,256]

  char* ws = (char*)d_ws;
  const size_t MB = 1024 * 1024;
  // Region 0..20MB: fp16 staging (x_h, anc_h, qk_h, v_wh) -- all dead before
  // fused_attn5 runs -- then overlaid by U4 (written by fused_attn5).
  half_t* x_h   = (half_t*)(ws);                  // 2 MB
  half_t* anc_h = (half_t*)(ws + 2 * MB);         // 1.25 MB
  half_t* qk_h  = (half_t*)(ws + 3407872);        // 0.5 MB  (3.25 MB)
  half_t* v_wh  = (half_t*)(ws + 3932160);        // 0.5 MB  (3.75 MB)
  half_t* U4    = (half_t*)(ws);                  // 20 MB (overlay)
  // Persistent region 20..28MB:
  half_t* pw_h     = (half_t*)(ws + 20 * MB);         // 0.5 MB
  half_t* q_h      = (half_t*)(ws + 20 * MB + 524288);  // 2 MB   (20.5)
  half_t* k_h      = (half_t*)(ws + 22 * MB + 524288);  // 1.25 MB(22.5)
  half_t* vT       = (half_t*)(ws + 24 * MB);           // 2 MB
  half_t* out_head = (half_t*)(ws + 26 * MB);           // 2 MB -> ends 28 MB

  cvt_all<<<dim3(2432), 256, 0, stream>>>(x, anchors, qk_w, v_w, proj_w,
                                          x_h, anc_h, qk_h, v_wh, pw_h);

  proj_all<<<dim3(84, 8), 256, 0, stream>>>(x_h, anc_h, qk_h, v_wh, q_h, k_h, vT);

  const size_t lds_bytes = 65536 + 32768 + 20480 + 16384 + 1024;  // 136,192 B
  fused_attn5<<<dim3(BB * NC * NH * 2), 1024, lds_bytes, stream>>>(q_h, k_h, vT, weights,
                                                                   a0_out, U4);

  reduce_u<<<dim3(512), 256, 0, stream>>>(U4, out_head);

  out_proj<<<dim3(32, 8), 256, 0, stream>>>(out_head, pw_h, proj_b, out0);

  (void)in_sizes; (void)n_in; (void)out_size; (void)ws_size;
}

// Round 8
// 115.694 us; speedup vs baseline: 1.6570x; 1.0057x over previous
//
#include <hip/hip_runtime.h>
#include <hip/hip_fp16.h>
#include <cstdint>

// Problem constants
#define BB 8
#define NN 256
#define NC 5
#define NH 8
#define DIM 512
#define HD 64

typedef _Float16 half_t;
typedef _Float16 h8 __attribute__((ext_vector_type(8)));
typedef _Float16 h4 __attribute__((ext_vector_type(4)));
typedef float f4 __attribute__((ext_vector_type(4)));
typedef uint32_t u4v __attribute__((ext_vector_type(4)));

__device__ __forceinline__ f4 mfma16(h8 a, h8 b, f4 c) {
  return __builtin_amdgcn_mfma_f32_16x16x32_f16(a, b, c, 0, 0, 0);
}

static __device__ const h8 HZERO = {(_Float16)0, (_Float16)0, (_Float16)0, (_Float16)0,
                                    (_Float16)0, (_Float16)0, (_Float16)0, (_Float16)0};

__device__ __forceinline__ h8 relu_pos_h8(h8 x) {
#if __has_builtin(__builtin_elementwise_max)
  return __builtin_elementwise_max(x, HZERO);
#else
  u4v u = __builtin_bit_cast(u4v, x);
  const u4v k1 = {0x00010001u, 0x00010001u, 0x00010001u, 0x00010001u};
  u4v s = (u >> 15) & k1;
  u4v m = (s << 16) - s;
  u = u & ~m;
  return __builtin_bit_cast(h8, u);
#endif
}

__device__ __forceinline__ h8 relu_neg_h8(h8 x) {
#if __has_builtin(__builtin_elementwise_max)
  return __builtin_elementwise_max(-x, HZERO);
#else
  u4v u = __builtin_bit_cast(u4v, x);
  const u4v k1 = {0x00010001u, 0x00010001u, 0x00010001u, 0x00010001u};
  const u4v ks = {0x80008000u, 0x80008000u, 0x80008000u, 0x80008000u};
  u4v s = (u >> 15) & k1;
  u4v m = (s << 16) - s;
  u = (u ^ ks) & m;
  return __builtin_bit_cast(h8, u);
#endif
}

// Raw barrier: waits LDS only, does NOT drain vmcnt (global stores stay in flight).
__device__ __forceinline__ void barrier_lds() {
  __builtin_amdgcn_sched_barrier(0);
  asm volatile("s_waitcnt lgkmcnt(0)" ::: "memory");
  __builtin_amdgcn_s_barrier();
  asm volatile("" ::: "memory");
  __builtin_amdgcn_sched_barrier(0);
}

// ---------------------------------------------------------------------------
// K0: convert x, anchors, qk_w, v_w, proj_w to fp16 (one f4->h4 per thread).
// chunks: x 262144 | anchors 163840 | qk 65536 | v 65536 | proj 65536
// ---------------------------------------------------------------------------
__global__ __launch_bounds__(256) void cvt_all(const float* __restrict__ x,
                                               const float* __restrict__ anchors,
                                               const float* __restrict__ qk_w,
                                               const float* __restrict__ v_w,
                                               const float* __restrict__ proj_w,
                                               half_t* __restrict__ x_h,
                                               half_t* __restrict__ anc_h,
                                               half_t* __restrict__ qk_h,
                                               half_t* __restrict__ v_wh,
                                               half_t* __restrict__ pw_h) {
  int i = blockIdx.x * 256 + threadIdx.x;
  const float* src;
  half_t* dst;
  int off;
  if (i < 262144)      { src = x;       dst = x_h;   off = i; }
  else if (i < 425984) { src = anchors; dst = anc_h; off = i - 262144; }
  else if (i < 491520) { src = qk_w;    dst = qk_h;  off = i - 425984; }
  else if (i < 557056) { src = v_w;     dst = v_wh;  off = i - 491520; }
  else                 { src = proj_w;  dst = pw_h;  off = i - 557056; }
  float4 v = ((const float4*)src)[off];
  h4 o;
  o[0] = (_Float16)v.x; o[1] = (_Float16)v.y; o[2] = (_Float16)v.z; o[3] = (_Float16)v.w;
  ((h4*)dst)[off] = o;
}

// ---------------------------------------------------------------------------
// K1: all three projections (pure fp16 operands).
//   bx <  32: q  = x_h @ qk_h^T   -> q_h [2048][512]
//   bx <  52: k  = anc_h @ qk_h^T -> k_h [1280][512]
//   else    : vT = (x_h @ v_wh^T)^T -> vT [512][2048]  ([h*64+d][b*256+m])
// ---------------------------------------------------------------------------
__global__ __launch_bounds__(256) void proj_all(const half_t* __restrict__ x_h,
                                                const half_t* __restrict__ anc_h,
                                                const half_t* __restrict__ qk_h,
                                                const half_t* __restrict__ v_wh,
                                                half_t* __restrict__ q_h,
                                                half_t* __restrict__ k_h,
                                                half_t* __restrict__ vT) {
  const int bx = blockIdx.x, by = blockIdx.y;
  const int tid = threadIdx.x;
  const int w = tid >> 6, lane = tid & 63;
  const int lr = lane & 15, lk = (lane >> 4) * 8, lg = lane >> 4;

  const half_t* A;
  const half_t* W;
  int mode, rt0;
  if (bx < 32)      { A = x_h;   W = qk_h; mode = 0; rt0 = bx * 64; }
  else if (bx < 52) { A = anc_h; W = qk_h; mode = 1; rt0 = (bx - 32) * 64; }
  else              { A = x_h;   W = v_wh; mode = 2; rt0 = (bx - 52) * 64; }

  const int row0 = rt0 + w * 16;
  const int col0 = by * 64;
  const f4 fz = {0.f, 0.f, 0.f, 0.f};
  f4 acc[4] = {fz, fz, fz, fz};
  const half_t* arow = A + (size_t)(row0 + lr) * DIM;

  if (mode != 2) {
    for (int k0 = 0; k0 < DIM; k0 += 32) {
      h8 a = *(const h8*)(arow + k0 + lk);
#pragma unroll
      for (int ct = 0; ct < 4; ++ct) {
        h8 b = *(const h8*)(W + (size_t)(col0 + ct * 16 + lr) * DIM + k0 + lk);
        acc[ct] = mfma16(a, b, acc[ct]);
      }
    }
    half_t* out = (mode == 0) ? q_h : k_h;
#pragma unroll
    for (int ct = 0; ct < 4; ++ct) {
      int col = col0 + ct * 16 + lr;
#pragma unroll
      for (int r = 0; r < 4; ++r) {
        int row = row0 + lg * 4 + r;
        out[(size_t)row * DIM + col] = (half_t)acc[ct][r];
      }
    }
  } else {
    for (int k0 = 0; k0 < DIM; k0 += 32) {
      h8 a = *(const h8*)(arow + k0 + lk);
#pragma unroll
      for (int ct = 0; ct < 4; ++ct) {
        h8 b = *(const h8*)(W + (size_t)(col0 + ct * 16 + lr) * DIM + k0 + lk);
        acc[ct] = mfma16(b, a, acc[ct]);
      }
    }
    const int xrow = row0 + lr;
#pragma unroll
    for (int ct = 0; ct < 4; ++ct) {
#pragma unroll
      for (int r = 0; r < 4; ++r) {
        int col = col0 + ct * 16 + lg * 4 + r;  // = h*64 + d
        vT[(size_t)col * (BB * NN) + xrow] = (half_t)acc[ct][r];
      }
    }
  }
}

// ---------------------------------------------------------------------------
// K2 (round-5 winner, unchanged): 2 half-blocks per (b,c,h), 1024 thr.
// ---------------------------------------------------------------------------
__global__ __launch_bounds__(1024, 4) void fused_attn5(const half_t* __restrict__ q_h,
                                                       const half_t* __restrict__ k_h,
                                                       const half_t* __restrict__ vT,
                                                       const float* __restrict__ weights,
                                                       float* __restrict__ a0_base,
                                                       half_t* __restrict__ U4) {
  extern __shared__ char smem[];
  half_t* a0s = (half_t*)smem;                        // [128][256] swz, 65536 B
  half_t* kst = (half_t*)(smem + 65536);              // [256][64] swz, 32768 B
  half_t* vst = kst;                                  // reuse: [64][128] swz, 16384 B
  half_t* wbuf = (half_t*)(smem + 98304);             // 16 waves x 640 h
  float2* scr = (float2*)(smem + 118784);             // [16 w][128 m'] f2, 16384 B
  float2* scr2 = (float2*)(smem + 135168);            // [128 m'] f2 (gm, sg), 1024 B

  const int id = blockIdx.x;          // 640 = 8*5*8*2
  const int b = id / 80;
  const int rem = id % 80;
  const int c = rem / 16;
  const int h = (rem >> 1) & 7;
  const int q = rem & 1;

  const int tid = threadIdx.x;
  const int w = tid >> 6, lane = tid & 63;
  const int lr = lane & 15, lk = (lane >> 4) * 8, lg = lane >> 4;
  const int n0 = w * 16;

  const half_t* qb = q_h + (size_t)(b * NN) * DIM + h * HD;
  const half_t* kb = k_h + (size_t)(c * NN) * DIM + h * HD;
  const half_t* vTb = vT + (size_t)(h * HD) * (BB * NN) + b * NN;
  float* a0out = a0_base + (size_t)((b * NC + c) * NH + h) * (NN * NN);
  const float wgt = weights[(b * NH + h) * NC + c];

  const f4 fz = {0.f, 0.f, 0.f, 0.f};

  // q fragments for this wave's 16 rows
  h8 qf0 = *(const h8*)(qb + (size_t)(n0 + lr) * DIM + lk);
  h8 qf1 = *(const h8*)(qb + (size_t)(n0 + lr) * DIM + 32 + lk);

  // ---- stage k tile [256][64] fp16, swizzled ----
#pragma unroll
  for (int pass = 0; pass < 2; ++pass) {
    int slot = pass * 1024 + tid;
    int row = slot >> 3, k8 = (slot & 7) * 8;
    h8 val = *(const h8*)(kb + (size_t)row * DIM + k8);
    *(h8*)(kst + ((row * 64 + k8) ^ ((row & 7) << 3))) = val;
  }
  barrier_lds();  // A

  // ---- phase 1: full a0 for L; half rows -> global fp32 + LDS fp16 ----
  half_t* Lb = wbuf + w * 640;  // [16][40]
  h8 La[8];
  const bool myhalf = ((w >> 3) == q);
  const int rl = (w & 7) * 16 + lr;  // local a0s row when myhalf
#pragma unroll
  for (int mt = 0; mt < 16; ++mt) {
    const int krow = mt * 16 + lr;
    h8 kf0 = *(const h8*)(kst + ((krow * 64 + lk) ^ ((krow & 7) << 3)));
    h8 kf1 = *(const h8*)(kst + ((krow * 64 + 32 + lk) ^ ((krow & 7) << 3)));
    f4 acc = mfma16(kf0, qf0, fz);
    acc = mfma16(kf1, qf1, acc);
    f4 v0;
    h4 hv;
#pragma unroll
    for (int r = 0; r < 4; ++r) {
      v0[r] = acc[r] * 0.125f;
      hv[r] = (_Float16)v0[r];
    }
    *(h4*)(Lb + lr * 40 + (mt & 1) * 16 + lg * 4) = hv;
    if (myhalf) {
      *(f4*)(a0out + (size_t)(n0 + lr) * NN + mt * 16 + lg * 4) = v0;
      *(h4*)(a0s + ((rl * 256 + mt * 16 + lg * 4) ^ ((rl & 7) << 3))) = hv;
    }
    if (mt & 1) {
      h8 raw = *(const h8*)(Lb + lr * 40 + lg * 8);
      La[mt >> 1] = relu_neg_h8(raw);
    }
  }
  barrier_lds();  // B (a0s ready; kst reads done)

  // ---- stage vT half-tile [64 d][128 m'] into dead kst region ----
  {
    int d = tid >> 4, m8 = (tid & 15) * 8;
    h8 val = *(const h8*)(vTb + (size_t)d * (BB * NN) + q * 128 + m8);
    *(h8*)(vst + ((d * 128 + m8) ^ ((d & 7) << 4))) = val;
  }

  // ---- S = L @ R^T over this block's 128 m' columns ----
  f4 sacc[8];
#pragma unroll
  for (int ct = 0; ct < 8; ++ct) sacc[ct] = fz;
#pragma unroll
  for (int kc = 0; kc < 8; ++kc) {
#pragma unroll
    for (int ct = 0; ct < 8; ++ct) {
      const int rr = ct * 16 + lr;
      h8 R = relu_pos_h8(*(const h8*)(a0s + ((rr * 256 + kc * 32 + lk) ^ ((rr & 7) << 3))));
      sacc[ct] = mfma16(La[kc], R, sacc[ct]);
    }
  }

  // ---- per-wave (max, sum) per column; exp in place ----
  float mw[8];
#pragma unroll
  for (int ct = 0; ct < 8; ++ct) {
    float v = 0.f;  // S >= 0 always
#pragma unroll
    for (int r = 0; r < 4; ++r) v = fmaxf(v, sacc[ct][r]);
    v = fmaxf(v, __shfl_xor(v, 16, 64));
    v = fmaxf(v, __shfl_xor(v, 32, 64));
    mw[ct] = v;
    float s = 0.f;
#pragma unroll
    for (int r = 0; r < 4; ++r) {
      float e = __expf(sacc[ct][r] - v);
      sacc[ct][r] = e;
      s += e;
    }
    s += __shfl_xor(s, 16, 64);
    s += __shfl_xor(s, 32, 64);
    if (lane < 16) {
      float2 t;
      t.x = v;
      t.y = s;
      scr[w * 128 + ct * 16 + lr] = t;
    }
  }
  barrier_lds();  // C

  // ---- combine across 16 waves: 128 threads, one column each ----
  if (tid < 128) {
    float gm = 0.f;
#pragma unroll
    for (int ww = 0; ww < 16; ++ww) gm = fmaxf(gm, scr[ww * 128 + tid].x);
    float sg = 0.f;
#pragma unroll
    for (int ww = 0; ww < 16; ++ww) {
      float2 t = scr[ww * 128 + tid];
      sg += t.y * __expf(t.x - gm);
    }
    float2 r;
    r.x = gm;
    r.y = sg;
    scr2[tid] = r;
  }
  barrier_lds();  // D

  float fac[8];
#pragma unroll
  for (int ct = 0; ct < 8; ++ct) {
    float2 t = scr2[ct * 16 + lr];
    fac[ct] = __expf(mw[ct] - t.x) * wgt / t.y;
  }

  // ---- PV: per 32-col panel, transpose-bounce P then MFMA with vst ----
  half_t* pbw = wbuf + w * 640;  // [32][20]
  f4 uacc[4] = {fz, fz, fz, fz};
#pragma unroll
  for (int pan = 0; pan < 4; ++pan) {
#pragma unroll
    for (int ctl = 0; ctl < 2; ++ctl) {
      const int ct = pan * 2 + ctl;
      h4 hv;
#pragma unroll
      for (int r = 0; r < 4; ++r) hv[r] = (_Float16)(sacc[ct][r] * fac[ct]);
      *(h4*)(pbw + (ctl * 16 + lr) * 20 + lg * 4) = hv;
    }
    h8 pf;
#pragma unroll
    for (int e = 0; e < 8; ++e) pf[e] = pbw[(lg * 8 + e) * 20 + lr];
#pragma unroll
    for (int dt = 0; dt < 4; ++dt) {
      const int dr = dt * 16 + lr;
      h8 vf = *(const h8*)(vst + ((dr * 128 + pan * 32 + lk) ^ ((dr & 7) << 4)));
      uacc[dt] = mfma16(vf, pf, uacc[dt]);
    }
  }

  // ---- store partial U4 (fp16): [n][d] ----
  half_t* U4b = U4 + (size_t)(((b * NC + c) * NH + h) * 2 + q) * (NN * HD);
#pragma unroll
  for (int dt = 0; dt < 4; ++dt) {
    h4 hv;
#pragma unroll
    for (int r = 0; r < 4; ++r) hv[r] = (_Float16)uacc[dt][r];
    *(h4*)(U4b + (size_t)(n0 + lr) * HD + dt * 16 + lg * 4) = hv;
  }
}

// ---------------------------------------------------------------------------
// K3: out_head[b,h] = sum over (c, half) of U4 partials
// ---------------------------------------------------------------------------
__global__ __launch_bounds__(256) void reduce_u(const half_t* __restrict__ U4,
                                                half_t* __restrict__ out_head) {
  int t = blockIdx.x * 256 + threadIdx.x;  // 131072 threads
  int bh = t >> 11;
  int e = (t & 2047) * 8;
  int b = bh >> 3, h = bh & 7;
  float acc[8] = {0.f, 0.f, 0.f, 0.f, 0.f, 0.f, 0.f, 0.f};
#pragma unroll
  for (int c = 0; c < NC; ++c)
#pragma unroll
    for (int qq = 0; qq < 2; ++qq) {
      h8 u = *(const h8*)(U4 + (size_t)(((b * NC + c) * NH + h) * 2 + qq) * (NN * HD) + e);
#pragma unroll
      for (int j = 0; j < 8; ++j) acc[j] += (float)u[j];
    }
  h8 o;
#pragma unroll
  for (int j = 0; j < 8; ++j) o[j] = (_Float16)acc[j];
  *(h8*)(out_head + (size_t)bh * (NN * HD) + e) = o;
}

// ---------------------------------------------------------------------------
// K4: out0 = reshape(out_head) @ pw_h^T + proj_b  (fp16 weights)
// ---------------------------------------------------------------------------
__global__ __launch_bounds__(256) void out_proj(const half_t* __restrict__ out_head,
                                                const half_t* __restrict__ pw_h,
                                                const float* __restrict__ pb,
                                                float* __restrict__ out0) {
  const int tid = threadIdx.x;
  const int w = tid >> 6, lane = tid & 63;
  const int lr = lane & 15, lk = (lane >> 4) * 8, lg = lane >> 4;
  const int row0 = blockIdx.x * 64 + w * 16;
  const int col0 = blockIdx.y * 64;
  const int r_ = row0 + lr;
  const int b = r_ >> 8, i = r_ & 255;
  const int hh = i >> 5;
  const f4 fz = {0.f, 0.f, 0.f, 0.f};
  f4 acc[4] = {fz, fz, fz, fz};
  for (int k0 = 0; k0 < DIM; k0 += 32) {
    const int k = k0 + lk;
    const int n = ((i & 31) << 3) | (k >> 6);
    const int d = k & 63;
    h8 a = *(const h8*)(out_head + (size_t)((b * NH + hh) * NN + n) * HD + d);
#pragma unroll
    for (int ct = 0; ct < 4; ++ct) {
      h8 bf = *(const h8*)(pw_h + (size_t)(col0 + ct * 16 + lr) * DIM + k0 + lk);
      acc[ct] = mfma16(a, bf, acc[ct]);
    }
  }
#pragma unroll
  for (int ct = 0; ct < 4; ++ct) {
    int col = col0 + ct * 16 + lr;
    float bias = pb[col];
#pragma unroll
    for (int r = 0; r < 4; ++r) {
      int row = row0 + lg * 4 + r;
      out0[(size_t)row * DIM + col] = acc[ct][r] + bias;
    }
  }
}

// ---------------------------------------------------------------------------
extern "C" void kernel_launch(void* const* d_in, const int* in_sizes, int n_in,
                              void* d_out, int out_size, void* d_ws, size_t ws_size,
                              hipStream_t stream) {
  const float* x = (const float*)d_in[0];
  const float* anchors = (const float*)d_in[1];
  const float* weights = (const float*)d_in[2];
  const float* qk_w = (const float*)d_in[3];
  const float* v_w = (const float*)d_in[4];
  const float* proj_w = (const float*)d_in[5];
  const float* proj_b = (const float*)d_in[6];

  float* out0 = (float*)d_out;                       // [8,256,512]
  float* a0_out = out0 + (size_t)BB * NN * DIM;      // [8,5,8,256,256]

  char* ws = (char*)d_ws;
  const size_t MB = 1024 * 1024;
  // Region 0..20MB: fp16 staging (x_h, anc_h, qk_h, v_wh) -- all dead before
  // fused_attn5 runs -- then overlaid by U4 (written by fused_attn5).
  half_t* x_h   = (half_t*)(ws);                  // 2 MB
  half_t* anc_h = (half_t*)(ws + 2 * MB);         // 1.25 MB
  half_t* qk_h  = (half_t*)(ws + 3407872);        // 0.5 MB  (3.25 MB)
  half_t* v_wh  = (half_t*)(ws + 3932160);        // 0.5 MB  (3.75 MB)
  half_t* U4    = (half_t*)(ws);                  // 20 MB (overlay)
  // Persistent region 20..28MB:
  half_t* pw_h     = (half_t*)(ws + 20 * MB);         // 0.5 MB
  half_t* q_h      = (half_t*)(ws + 20 * MB + 524288);  // 2 MB   (20.5)
  half_t* k_h      = (half_t*)(ws + 22 * MB + 524288);  // 1.25 MB(22.5)
  half_t* vT       = (half_t*)(ws + 24 * MB);           // 2 MB
  half_t* out_head = (half_t*)(ws + 26 * MB);           // 2 MB -> ends 28 MB

  cvt_all<<<dim3(2432), 256, 0, stream>>>(x, anchors, qk_w, v_w, proj_w,
                                          x_h, anc_h, qk_h, v_wh, pw_h);

  proj_all<<<dim3(84, 8), 256, 0, stream>>>(x_h, anc_h, qk_h, v_wh, q_h, k_h, vT);

  const size_t lds_bytes = 65536 + 32768 + 20480 + 16384 + 1024;  // 136,192 B
  fused_attn5<<<dim3(BB * NC * NH * 2), 1024, lds_bytes, stream>>>(q_h, k_h, vT, weights,
                                                                   a0_out, U4);

  reduce_u<<<dim3(512), 256, 0, stream>>>(U4, out_head);

  out_proj<<<dim3(32, 8), 256, 0, stream>>>(out_head, pw_h, proj_b, out0);

  (void)in_sizes; (void)n_in; (void)out_size; (void)ws_size;
}